// Round 9
// baseline (258.772 us; speedup 1.0000x reference)
//
#include <hip/hip_runtime.h>

constexpr int NFEAT  = 256;
constexpr int NHID   = 128;
constexpr int NCLASS = 64;

typedef __attribute__((ext_vector_type(8))) short short8;   // 8 bf16 (4 VGPRs)
typedef __attribute__((ext_vector_type(4))) float floatx4;  // MFMA accumulator

__device__ __forceinline__ unsigned short f2bf(float x) {
    unsigned u = __float_as_uint(x);
    u += 0x7FFFu + ((u >> 16) & 1u);   // RNE
    return (unsigned short)(u >> 16);
}
__device__ __forceinline__ float bf_lo(unsigned int p) { return __uint_as_float(p << 16); }
__device__ __forceinline__ float bf_hi(unsigned int p) { return __uint_as_float(p & 0xFFFF0000u); }

constexpr int EPB = 8192;   // edges per partition block

// ---------------- fused: bucket histogram (blocks < pgrid) + W cast (rest) ----------------
__global__ __launch_bounds__(256) void fused_cast_count_kernel(
    const int* __restrict__ dst, int* __restrict__ bcnt, int E, int nbuk, int pgrid,
    const float* __restrict__ W1, const float* __restrict__ W2,
    unsigned short* __restrict__ W1T, unsigned short* __restrict__ W2T)
{
    __shared__ int cnt[512];
    if ((int)blockIdx.x < pgrid) {
        for (int i = threadIdx.x; i < 512; i += 256) cnt[i] = 0;
        __syncthreads();
        int begin = blockIdx.x * EPB;
        int endi = begin + EPB; if (endi > E) endi = E;
        for (int i = begin + threadIdx.x; i < endi; i += 256)
            atomicAdd(&cnt[dst[i] >> 8], 1);
        __syncthreads();
        for (int b = threadIdx.x; b < nbuk; b += 256)
            if (cnt[b]) atomicAdd(&bcnt[b], cnt[b]);
    } else {
        int i = (blockIdx.x - pgrid) * 256 + threadIdx.x;
        if (i < NFEAT * NHID) {         // 256x128
            int k = i >> 7, n = i & 127;
            W1T[n * NFEAT + k] = f2bf(W1[i]);
        }
        if (i < NHID * NCLASS) {        // 128x64
            int k = i >> 6, n = i & 63;
            W2T[n * NHID + k] = f2bf(W2[i]);
        }
    }
}

// ---------------- full-K staged MFMA GEMM, register burst guaranteed by launch bounds ----
// C[M][BN] bf16 = A[M][KTOT] @ BT^T.  BT bf16 [BN][KTOT] (small, L1/L2-resident).
// Entire K-extent of a BM-row band staged to XOR-swizzled LDS in ONE burst
// (16 outstanding dwordx4/thread held in registers -> __launch_bounds__(256,2)).
template<int BN, int KTOT, bool A_IS_F32, int BM>
__global__ __launch_bounds__(256, 2) void gemm_fullk_kernel(
    const void* __restrict__ Aptr,
    const unsigned short* __restrict__ BT,
    unsigned short* __restrict__ C,
    int M)
{
    constexpr int NF   = BN / 16;
    constexpr int MF   = BM / 64;        // wave owns BM/4 rows = MF*16
    constexpr int NKS  = KTOT / 32;
    constexpr int ROWB = KTOT * 2;       // LDS row bytes
    __shared__ unsigned short As[BM * KTOT];

    const int tid = threadIdx.x;
    const int w = tid >> 6, l = tid & 63;
    const int row0 = blockIdx.x * BM;

    // ---- stage A (full K), swizzled: byte ^= (row&7)<<4 ----
    if constexpr (A_IS_F32) {
        constexpr int F4R = KTOT / 4;                 // float4 per row
        constexpr int NLD = BM * F4R / 256;           // float4 loads per thread (16)
        const float* A = (const float*)Aptr;
        float4 pa[NLD];
        #pragma unroll
        for (int i = 0; i < NLD; ++i) {
            int idx = i * 256 + tid;
            int r = idx / F4R, f4 = idx % F4R;
            int row = row0 + r; if (row >= M) row = M - 1;
            pa[i] = *reinterpret_cast<const float4*>(A + (size_t)row * KTOT + f4 * 4);
        }
        #pragma unroll
        for (int i = 0; i < NLD; ++i) {
            int idx = i * 256 + tid;
            int r = idx / F4R, f4 = idx % F4R;
            ushort4 b;
            b.x = f2bf(pa[i].x); b.y = f2bf(pa[i].y); b.z = f2bf(pa[i].z); b.w = f2bf(pa[i].w);
            int byte = (f4 * 8) ^ ((r & 7) << 4);
            *reinterpret_cast<ushort4*>(reinterpret_cast<char*>(As) + r * ROWB + byte) = b;
        }
    } else {
        constexpr int CPR = KTOT / 8;                 // 16B chunks per row
        constexpr int NLD = BM * CPR / 256;           // uint4 loads per thread (8)
        const unsigned short* A = (const unsigned short*)Aptr;
        uint4 pa[NLD];
        #pragma unroll
        for (int i = 0; i < NLD; ++i) {
            int idx = i * 256 + tid;
            int r = idx / CPR, c = idx % CPR;
            int row = row0 + r; if (row >= M) row = M - 1;
            pa[i] = *reinterpret_cast<const uint4*>(A + (size_t)row * KTOT + c * 8);
        }
        #pragma unroll
        for (int i = 0; i < NLD; ++i) {
            int idx = i * 256 + tid;
            int r = idx / CPR, c = idx % CPR;
            int byte = (c * 16) ^ ((r & 7) << 4);
            *reinterpret_cast<uint4*>(reinterpret_cast<char*>(As) + r * ROWB + byte) = pa[i];
        }
    }
    __syncthreads();

    // ---- compute: wave w owns rows [w*BM/4, (w+1)*BM/4) x all BN cols ----
    floatx4 acc[MF][NF];
    #pragma unroll
    for (int i = 0; i < MF; ++i)
        #pragma unroll
        for (int j = 0; j < NF; ++j) acc[i][j] = (floatx4){0.f, 0.f, 0.f, 0.f};

    const int wrow = w * (BM / 4);
    const int lr = l & 15, lk = l >> 4;
    #pragma unroll
    for (int ks = 0; ks < NKS; ++ks) {
        short8 a[MF];
        #pragma unroll
        for (int mf = 0; mf < MF; ++mf) {
            int r = wrow + mf * 16 + lr;
            int byte = (ks * 64 + lk * 16) ^ ((r & 7) << 4);
            a[mf] = *reinterpret_cast<const short8*>(reinterpret_cast<const char*>(As) + r * ROWB + byte);
        }
        #pragma unroll
        for (int nf = 0; nf < NF; ++nf) {
            const int n = nf * 16 + lr;
            short8 b = *reinterpret_cast<const short8*>(BT + (size_t)n * KTOT + ks * 32 + lk * 8);
            #pragma unroll
            for (int mf = 0; mf < MF; ++mf)
                acc[mf][nf] = __builtin_amdgcn_mfma_f32_16x16x32_bf16(a[mf], b, acc[mf][nf], 0, 0, 0);
        }
    }
    // epilogue: C/D layout col = lane&15, row = (lane>>4)*4 + reg
    const int cr = lk * 4, cc = lr;
    #pragma unroll
    for (int mf = 0; mf < MF; ++mf)
        #pragma unroll
        for (int nf = 0; nf < NF; ++nf)
            #pragma unroll
            for (int q = 0; q < 4; ++q) {
                int row = row0 + wrow + mf * 16 + cr + q;
                if (row < M) C[(size_t)row * BN + nf * 16 + cc] = f2bf(acc[mf][nf][q]);
            }
}

// ---------------- two-level CSR build (coalesced writes) ----------------
// bucket b = dst >> 8 (256 rows per bucket); nbuk <= 512; pack = src | (dst&255)<<17

__global__ __launch_bounds__(512) void bucket_scan_kernel(
    const int* __restrict__ bcnt, int* __restrict__ bb, int* __restrict__ bcur,
    int* __restrict__ row_ptr, int nbuk, int M, int E)
{
    __shared__ int s[512];
    int t = threadIdx.x;
    int v = (t < nbuk) ? bcnt[t] : 0;
    s[t] = v;
    __syncthreads();
    for (int off = 1; off < 512; off <<= 1) {
        int u = (t >= off) ? s[t - off] : 0;
        __syncthreads();
        s[t] += u;
        __syncthreads();
    }
    if (t < nbuk) {
        int excl = s[t] - v;
        bb[t] = excl;
        bcur[t] = excl;
    }
    if (t == 0) { bb[nbuk] = E; row_ptr[M] = E; }
}

__global__ __launch_bounds__(256) void bucket_scatter_kernel(
    const float* __restrict__ vals, const int* __restrict__ src,
    const int* __restrict__ dst, int* __restrict__ bcur,
    int2* __restrict__ tmp, int E)
{
    __shared__ int cnt[512];
    __shared__ int base[512];
    for (int i = threadIdx.x; i < 512; i += 256) cnt[i] = 0;
    __syncthreads();
    int begin = blockIdx.x * EPB;
    int endi = begin + EPB; if (endi > E) endi = E;
    for (int i = begin + threadIdx.x; i < endi; i += 256)
        atomicAdd(&cnt[dst[i] >> 8], 1);
    __syncthreads();
    for (int b = threadIdx.x; b < 512; b += 256) {
        int c = cnt[b];
        base[b] = c ? atomicAdd(&bcur[b], c) : 0;
        cnt[b] = 0;
    }
    __syncthreads();
    for (int i = begin + threadIdx.x; i < endi; i += 256) {
        int d = dst[i];
        int b = d >> 8;
        int pos = base[b] + atomicAdd(&cnt[b], 1);
        tmp[pos] = make_int2(src[i] | ((d & 255) << 17), __float_as_int(vals[i]));
    }
}

__global__ __launch_bounds__(256) void bucket_fine_kernel(
    const int* __restrict__ bb, const int2* __restrict__ tmp,
    int* __restrict__ row_ptr, int2* __restrict__ pairs, int M)
{
    __shared__ int cnt[256];
    __shared__ int excl[256];
    __shared__ int cur[256];
    const int b = blockIdx.x;
    const int beg = bb[b], endi = bb[b + 1];
    const int t = threadIdx.x;
    cnt[t] = 0;
    __syncthreads();
    for (int j = beg + t; j < endi; j += 256)
        atomicAdd(&cnt[(tmp[j].x >> 17) & 255], 1);
    __syncthreads();
    int v = cnt[t];
    excl[t] = v;
    __syncthreads();
    for (int off = 1; off < 256; off <<= 1) {
        int u = (t >= off) ? excl[t - off] : 0;
        __syncthreads();
        excl[t] += u;
        __syncthreads();
    }
    int ex = excl[t] - v;
    excl[t] = ex;
    cur[t] = 0;
    int row = (b << 8) + t;
    if (row < M) row_ptr[row] = beg + ex;
    __syncthreads();
    for (int j = beg + t; j < endi; j += 256) {
        int2 p = tmp[j];
        int dl = (p.x >> 17) & 255;
        int pos = beg + excl[dl] + atomicAdd(&cur[dl], 1);
        pairs[pos] = p;
    }
}

// ---------------- gather SPMM, bf16 dense, 16/8-lane row groups ----------------

// D=128: 16-lane group per dst row (4 rows/wave, 16 rows/block). Output: relu -> bf16.
__global__ __launch_bounds__(256) void spmm_gather128_kernel(
    const int*  __restrict__ row_ptr,
    const int2* __restrict__ pairs,
    const unsigned short* __restrict__ dense,   // bf16 [M][128]
    unsigned short*       __restrict__ outbf,   // bf16 [M][128] = relu(sum)
    int M)
{
    const int wv = threadIdx.x >> 6, l = threadIdx.x & 63;
    const int g = l >> 4, t = l & 15;
    const int row = blockIdx.x * 16 + wv * 4 + g;
    int beg = 0, end = 0;
    if (row < M) { beg = row_ptr[row]; end = row_ptr[row + 1]; }
    const uint4* d4 = reinterpret_cast<const uint4*>(dense);  // row = 16 uint4
    float2 a0 = {0.f, 0.f}, a1 = {0.f, 0.f}, a2 = {0.f, 0.f}, a3 = {0.f, 0.f};
    int j = beg;
    for (; j + 4 <= end; j += 4) {
        int2 p0 = pairs[j], p1 = pairs[j + 1], p2 = pairs[j + 2], p3 = pairs[j + 3];
        uint4 x0 = d4[(size_t)(p0.x & 0x1FFFF) * 16 + t];
        uint4 x1 = d4[(size_t)(p1.x & 0x1FFFF) * 16 + t];
        uint4 x2 = d4[(size_t)(p2.x & 0x1FFFF) * 16 + t];
        uint4 x3 = d4[(size_t)(p3.x & 0x1FFFF) * 16 + t];
        float v0 = __int_as_float(p0.y), v1 = __int_as_float(p1.y);
        float v2 = __int_as_float(p2.y), v3 = __int_as_float(p3.y);
        a0.x += v0 * bf_lo(x0.x); a0.y += v0 * bf_hi(x0.x);
        a1.x += v0 * bf_lo(x0.y); a1.y += v0 * bf_hi(x0.y);
        a2.x += v0 * bf_lo(x0.z); a2.y += v0 * bf_hi(x0.z);
        a3.x += v0 * bf_lo(x0.w); a3.y += v0 * bf_hi(x0.w);
        a0.x += v1 * bf_lo(x1.x); a0.y += v1 * bf_hi(x1.x);
        a1.x += v1 * bf_lo(x1.y); a1.y += v1 * bf_hi(x1.y);
        a2.x += v1 * bf_lo(x1.z); a2.y += v1 * bf_hi(x1.z);
        a3.x += v1 * bf_lo(x1.w); a3.y += v1 * bf_hi(x1.w);
        a0.x += v2 * bf_lo(x2.x); a0.y += v2 * bf_hi(x2.x);
        a1.x += v2 * bf_lo(x2.y); a1.y += v2 * bf_hi(x2.y);
        a2.x += v2 * bf_lo(x2.z); a2.y += v2 * bf_hi(x2.z);
        a3.x += v2 * bf_lo(x2.w); a3.y += v2 * bf_hi(x2.w);
        a0.x += v3 * bf_lo(x3.x); a0.y += v3 * bf_hi(x3.x);
        a1.x += v3 * bf_lo(x3.y); a1.y += v3 * bf_hi(x3.y);
        a2.x += v3 * bf_lo(x3.z); a2.y += v3 * bf_hi(x3.z);
        a3.x += v3 * bf_lo(x3.w); a3.y += v3 * bf_hi(x3.w);
    }
    for (; j < end; ++j) {
        int2 p = pairs[j];
        uint4 x = d4[(size_t)(p.x & 0x1FFFF) * 16 + t];
        float v = __int_as_float(p.y);
        a0.x += v * bf_lo(x.x); a0.y += v * bf_hi(x.x);
        a1.x += v * bf_lo(x.y); a1.y += v * bf_hi(x.y);
        a2.x += v * bf_lo(x.z); a2.y += v * bf_hi(x.z);
        a3.x += v * bf_lo(x.w); a3.y += v * bf_hi(x.w);
    }
    if (row < M) {
        uint4 o;
        o.x = (unsigned)f2bf(fmaxf(a0.x, 0.f)) | ((unsigned)f2bf(fmaxf(a0.y, 0.f)) << 16);
        o.y = (unsigned)f2bf(fmaxf(a1.x, 0.f)) | ((unsigned)f2bf(fmaxf(a1.y, 0.f)) << 16);
        o.z = (unsigned)f2bf(fmaxf(a2.x, 0.f)) | ((unsigned)f2bf(fmaxf(a2.y, 0.f)) << 16);
        o.w = (unsigned)f2bf(fmaxf(a3.x, 0.f)) | ((unsigned)f2bf(fmaxf(a3.y, 0.f)) << 16);
        reinterpret_cast<uint4*>(outbf)[(size_t)row * 16 + t] = o;
    }
}

// D=64: 8-lane group per dst row (8 rows/wave, 32 rows/block). Output f32.
__global__ __launch_bounds__(256) void spmm_gather64_kernel(
    const int*  __restrict__ row_ptr,
    const int2* __restrict__ pairs,
    const unsigned short* __restrict__ dense,   // bf16 [M][64]
    float*                __restrict__ out,     // f32 [M][64]
    int M)
{
    const int wv = threadIdx.x >> 6, l = threadIdx.x & 63;
    const int g = l >> 3, t = l & 7;
    const int row = blockIdx.x * 32 + wv * 8 + g;
    int beg = 0, end = 0;
    if (row < M) { beg = row_ptr[row]; end = row_ptr[row + 1]; }
    const uint4* d4 = reinterpret_cast<const uint4*>(dense);  // row = 8 uint4
    float2 a0 = {0.f, 0.f}, a1 = {0.f, 0.f}, a2 = {0.f, 0.f}, a3 = {0.f, 0.f};
    int j = beg;
    for (; j + 4 <= end; j += 4) {
        int2 p0 = pairs[j], p1 = pairs[j + 1], p2 = pairs[j + 2], p3 = pairs[j + 3];
        uint4 x0 = d4[(size_t)(p0.x & 0x1FFFF) * 8 + t];
        uint4 x1 = d4[(size_t)(p1.x & 0x1FFFF) * 8 + t];
        uint4 x2 = d4[(size_t)(p2.x & 0x1FFFF) * 8 + t];
        uint4 x3 = d4[(size_t)(p3.x & 0x1FFFF) * 8 + t];
        float v0 = __int_as_float(p0.y), v1 = __int_as_float(p1.y);
        float v2 = __int_as_float(p2.y), v3 = __int_as_float(p3.y);
        a0.x += v0 * bf_lo(x0.x); a0.y += v0 * bf_hi(x0.x);
        a1.x += v0 * bf_lo(x0.y); a1.y += v0 * bf_hi(x0.y);
        a2.x += v0 * bf_lo(x0.z); a2.y += v0 * bf_hi(x0.z);
        a3.x += v0 * bf_lo(x0.w); a3.y += v0 * bf_hi(x0.w);
        a0.x += v1 * bf_lo(x1.x); a0.y += v1 * bf_hi(x1.x);
        a1.x += v1 * bf_lo(x1.y); a1.y += v1 * bf_hi(x1.y);
        a2.x += v1 * bf_lo(x1.z); a2.y += v1 * bf_hi(x1.z);
        a3.x += v1 * bf_lo(x1.w); a3.y += v1 * bf_hi(x1.w);
        a0.x += v2 * bf_lo(x2.x); a0.y += v2 * bf_hi(x2.x);
        a1.x += v2 * bf_lo(x2.y); a1.y += v2 * bf_hi(x2.y);
        a2.x += v2 * bf_lo(x2.z); a2.y += v2 * bf_hi(x2.z);
        a3.x += v2 * bf_lo(x2.w); a3.y += v2 * bf_hi(x2.w);
        a0.x += v3 * bf_lo(x3.x); a0.y += v3 * bf_hi(x3.x);
        a1.x += v3 * bf_lo(x3.y); a1.y += v3 * bf_hi(x3.y);
        a2.x += v3 * bf_lo(x3.z); a2.y += v3 * bf_hi(x3.z);
        a3.x += v3 * bf_lo(x3.w); a3.y += v3 * bf_hi(x3.w);
    }
    for (; j < end; ++j) {
        int2 p = pairs[j];
        uint4 x = d4[(size_t)(p.x & 0x1FFFF) * 8 + t];
        float v = __int_as_float(p.y);
        a0.x += v * bf_lo(x.x); a0.y += v * bf_hi(x.x);
        a1.x += v * bf_lo(x.y); a1.y += v * bf_hi(x.y);
        a2.x += v * bf_lo(x.z); a2.y += v * bf_hi(x.z);
        a3.x += v * bf_lo(x.w); a3.y += v * bf_hi(x.w);
    }
    if (row < M) {
        float4 o0 = make_float4(a0.x, a0.y, a1.x, a1.y);
        float4 o1 = make_float4(a2.x, a2.y, a3.x, a3.y);
        float4* op = reinterpret_cast<float4*>(out + (size_t)row * 64 + t * 8);
        op[0] = o0;
        op[1] = o1;
    }
}

extern "C" void kernel_launch(void* const* d_in, const int* in_sizes, int n_in,
                              void* d_out, int out_size, void* d_ws, size_t ws_size,
                              hipStream_t stream) {
    const float* x  = (const float*)d_in[0];
    const float* W1 = (const float*)d_in[1];
    const float* W2 = (const float*)d_in[2];
    const float* ev = (const float*)d_in[3];
    const int*   es = (const int*)d_in[4];
    const int*   ed = (const int*)d_in[5];
    float* out = (float*)d_out;

    const int M = in_sizes[0] / NFEAT;   // 100000
    const int E = in_sizes[3];           // 1.6M
    const int nbuk = (M + 255) >> 8;     // 391

    size_t off = 0;
    auto alloc = [&](size_t bytes) -> void* {
        void* p = (char*)d_ws + off;
        off += (bytes + 255) & ~(size_t)255;
        return p;
    };
    unsigned short* sup_bf  = (unsigned short*)alloc((size_t)M * NHID * 2);
    unsigned short* h_bf    = (unsigned short*)alloc((size_t)M * NHID * 2);
    unsigned short* sup2_bf = (unsigned short*)alloc((size_t)M * NCLASS * 2);
    unsigned short* W1T     = (unsigned short*)alloc((size_t)NHID * NFEAT * 2);
    unsigned short* W2T     = (unsigned short*)alloc((size_t)NCLASS * NHID * 2);
    int*  row_ptr = (int*) alloc((size_t)(M + 1) * sizeof(int));
    int*  bcnt    = (int*) alloc(512 * sizeof(int));
    int*  bb      = (int*) alloc(513 * sizeof(int));
    int*  bcur    = (int*) alloc(512 * sizeof(int));
    int2* tmp     = (int2*)alloc((size_t)E * sizeof(int2));
    int2* pairs   = (int2*)alloc((size_t)E * sizeof(int2));
    (void)ws_size;

    const int pgrid = (E + EPB - 1) / EPB;
    const int castg = (NFEAT * NHID + 255) / 256;

    // count + weight-cast fused (independent work, one launch)
    hipMemsetAsync(bcnt, 0, 512 * sizeof(int), stream);
    fused_cast_count_kernel<<<pgrid + castg, 256, 0, stream>>>(
        ed, bcnt, E, nbuk, pgrid, W1, W2, W1T, W2T);

    // GEMM1: full-K staged (BM=64, K=256 in LDS, one barrier, real 16-deep burst)
    gemm_fullk_kernel<NHID, NFEAT, true, 64><<<(M + 63) / 64, 256, 0, stream>>>(x, W1T, sup_bf, M);

    bucket_scan_kernel<<<1, 512, 0, stream>>>(bcnt, bb, bcur, row_ptr, nbuk, M, E);
    bucket_scatter_kernel<<<pgrid, 256, 0, stream>>>(ev, es, ed, bcur, tmp, E);
    bucket_fine_kernel<<<nbuk, 256, 0, stream>>>(bb, tmp, row_ptr, pairs, M);

    spmm_gather128_kernel<<<(M + 15) / 16, 256, 0, stream>>>(row_ptr, pairs, sup_bf, h_bf, M);

    // GEMM2: full-K staged (BM=128, K=128 in LDS)
    gemm_fullk_kernel<NCLASS, NHID, false, 128><<<(M + 127) / 128, 256, 0, stream>>>(h_bf, W2T, sup2_bf, M);

    spmm_gather64_kernel<<<(M + 31) / 32, 256, 0, stream>>>(row_ptr, pairs, sup2_bf, out, M);
}

// Round 10
// 208.555 us; speedup vs baseline: 1.2408x; 1.2408x over previous
//
#include <hip/hip_runtime.h>

constexpr int NFEAT  = 256;
constexpr int NHID   = 128;
constexpr int NCLASS = 64;

typedef __attribute__((ext_vector_type(8))) short short8;   // 8 bf16 (4 VGPRs)
typedef __attribute__((ext_vector_type(4))) float floatx4;  // MFMA accumulator

__device__ __forceinline__ unsigned short f2bf(float x) {
    unsigned u = __float_as_uint(x);
    u += 0x7FFFu + ((u >> 16) & 1u);   // RNE
    return (unsigned short)(u >> 16);
}
__device__ __forceinline__ float bf_lo(unsigned int p) { return __uint_as_float(p << 16); }
__device__ __forceinline__ float bf_hi(unsigned int p) { return __uint_as_float(p & 0xFFFF0000u); }

constexpr int EPB = 8192;   // edges per partition block

// ---------------- fused: bucket histogram (blocks < pgrid) + W cast (rest) ----------------
__global__ __launch_bounds__(256) void fused_cast_count_kernel(
    const int* __restrict__ dst, int* __restrict__ bcnt, int E, int nbuk, int pgrid,
    const float* __restrict__ W1, const float* __restrict__ W2,
    unsigned short* __restrict__ W1T, unsigned short* __restrict__ W2T)
{
    __shared__ int cnt[512];
    if ((int)blockIdx.x < pgrid) {
        for (int i = threadIdx.x; i < 512; i += 256) cnt[i] = 0;
        __syncthreads();
        int begin = blockIdx.x * EPB;
        int endi = begin + EPB; if (endi > E) endi = E;
        for (int i = begin + threadIdx.x; i < endi; i += 256)
            atomicAdd(&cnt[dst[i] >> 8], 1);
        __syncthreads();
        for (int b = threadIdx.x; b < nbuk; b += 256)
            if (cnt[b]) atomicAdd(&bcnt[b], cnt[b]);
    } else {
        int i = (blockIdx.x - pgrid) * 256 + threadIdx.x;
        if (i < NFEAT * NHID) {         // 256x128
            int k = i >> 7, n = i & 127;
            W1T[n * NFEAT + k] = f2bf(W1[i]);
        }
        if (i < NHID * NCLASS) {        // 128x64
            int k = i >> 6, n = i & 63;
            W2T[n * NHID + k] = f2bf(W2[i]);
        }
    }
}

// ---------------- MFMA GEMM (round-3/5 proven 63us structure): BM=64, 2-phase ----------
template<int BN, int KTOT, bool A_IS_F32>
__global__ __launch_bounds__(256) void gemm_mfma_kernel(
    const void* __restrict__ Aptr,
    const unsigned short* __restrict__ BT,
    unsigned short* __restrict__ C,
    int M)
{
    constexpr int NB  = BN / 16;
    constexpr int LDA = 72;                 // shorts: 64+8 pad -> 144B stride (2-way banks, free)
    __shared__ unsigned short As[64 * LDA];
    __shared__ unsigned short Bs[BN * LDA];
    const int tid = threadIdx.x;
    const int w   = tid >> 6;
    const int l   = tid & 63;
    const int row0 = blockIdx.x * 64;

    floatx4 acc[NB];
    #pragma unroll
    for (int i = 0; i < NB; ++i) acc[i] = (floatx4){0.f, 0.f, 0.f, 0.f};

    for (int k0 = 0; k0 < KTOT; k0 += 64) {
        if constexpr (A_IS_F32) {
            const float* A = (const float*)Aptr;
            #pragma unroll
            for (int i = 0; i < 4; ++i) {
                int c = tid + 256 * i;
                int r = c >> 4, k4 = (c & 15) * 4;
                int row = row0 + r;
                float4 v = (row < M) ? *reinterpret_cast<const float4*>(A + (size_t)row * KTOT + k0 + k4)
                                     : make_float4(0.f, 0.f, 0.f, 0.f);
                ushort4 b;
                b.x = f2bf(v.x); b.y = f2bf(v.y); b.z = f2bf(v.z); b.w = f2bf(v.w);
                *reinterpret_cast<ushort4*>(&As[r * LDA + k4]) = b;
            }
        } else {
            const unsigned short* A = (const unsigned short*)Aptr;
            #pragma unroll
            for (int i = 0; i < 2; ++i) {
                int c = tid + 256 * i;
                int r = c >> 3, k8 = (c & 7) * 8;
                int row = row0 + r;
                uint4 v = (row < M) ? *reinterpret_cast<const uint4*>(A + (size_t)row * KTOT + k0 + k8)
                                    : make_uint4(0u, 0u, 0u, 0u);
                *reinterpret_cast<uint4*>(&As[r * LDA + k8]) = v;
            }
        }
        #pragma unroll
        for (int i = 0; i < BN * 8 / 256; ++i) {
            int c = tid + 256 * i;
            int n = c >> 3, k8 = (c & 7) * 8;
            uint4 v = *reinterpret_cast<const uint4*>(BT + (size_t)n * KTOT + k0 + k8);
            *reinterpret_cast<uint4*>(&Bs[n * LDA + k8]) = v;
        }
        __syncthreads();
        #pragma unroll
        for (int ks = 0; ks < 2; ++ks) {
            short8 a = *reinterpret_cast<const short8*>(&As[(16 * w + (l & 15)) * LDA + ks * 32 + (l >> 4) * 8]);
            #pragma unroll
            for (int nb = 0; nb < NB; ++nb) {
                short8 b = *reinterpret_cast<const short8*>(&Bs[(16 * nb + (l & 15)) * LDA + ks * 32 + (l >> 4) * 8]);
                acc[nb] = __builtin_amdgcn_mfma_f32_16x16x32_bf16(a, b, acc[nb], 0, 0, 0);
            }
        }
        __syncthreads();
    }
    const int cr = (l >> 4) * 4;
    const int cc = l & 15;
    #pragma unroll
    for (int nb = 0; nb < NB; ++nb) {
        #pragma unroll
        for (int r = 0; r < 4; ++r) {
            int row = row0 + 16 * w + cr + r;
            if (row < M) C[(size_t)row * BN + 16 * nb + cc] = f2bf(acc[nb][r]);
        }
    }
}

// ---------------- two-level CSR build (coalesced writes) ----------------
// bucket b = dst >> 8 (256 rows per bucket); nbuk <= 512; pack = src | (dst&255)<<17

__global__ __launch_bounds__(512) void bucket_scan_kernel(
    const int* __restrict__ bcnt, int* __restrict__ bb, int* __restrict__ bcur,
    int* __restrict__ row_ptr, int nbuk, int M, int E)
{
    __shared__ int s[512];
    int t = threadIdx.x;
    int v = (t < nbuk) ? bcnt[t] : 0;
    s[t] = v;
    __syncthreads();
    for (int off = 1; off < 512; off <<= 1) {
        int u = (t >= off) ? s[t - off] : 0;
        __syncthreads();
        s[t] += u;
        __syncthreads();
    }
    if (t < nbuk) {
        int excl = s[t] - v;
        bb[t] = excl;
        bcur[t] = excl;
    }
    if (t == 0) { bb[nbuk] = E; row_ptr[M] = E; }
}

__global__ __launch_bounds__(256) void bucket_scatter_kernel(
    const float* __restrict__ vals, const int* __restrict__ src,
    const int* __restrict__ dst, int* __restrict__ bcur,
    int2* __restrict__ tmp, int E)
{
    __shared__ int cnt[512];
    __shared__ int base[512];
    for (int i = threadIdx.x; i < 512; i += 256) cnt[i] = 0;
    __syncthreads();
    int begin = blockIdx.x * EPB;
    int endi = begin + EPB; if (endi > E) endi = E;
    for (int i = begin + threadIdx.x; i < endi; i += 256)
        atomicAdd(&cnt[dst[i] >> 8], 1);
    __syncthreads();
    for (int b = threadIdx.x; b < 512; b += 256) {
        int c = cnt[b];
        base[b] = c ? atomicAdd(&bcur[b], c) : 0;
        cnt[b] = 0;
    }
    __syncthreads();
    for (int i = begin + threadIdx.x; i < endi; i += 256) {
        int d = dst[i];
        int b = d >> 8;
        int pos = base[b] + atomicAdd(&cnt[b], 1);
        tmp[pos] = make_int2(src[i] | ((d & 255) << 17), __float_as_int(vals[i]));
    }
}

__global__ __launch_bounds__(256) void bucket_fine_kernel(
    const int* __restrict__ bb, const int2* __restrict__ tmp,
    int* __restrict__ row_ptr, int2* __restrict__ pairs, int M)
{
    __shared__ int cnt[256];
    __shared__ int excl[256];
    __shared__ int cur[256];
    const int b = blockIdx.x;
    const int beg = bb[b], endi = bb[b + 1];
    const int t = threadIdx.x;
    cnt[t] = 0;
    __syncthreads();
    for (int j = beg + t; j < endi; j += 256)
        atomicAdd(&cnt[(tmp[j].x >> 17) & 255], 1);
    __syncthreads();
    int v = cnt[t];
    excl[t] = v;
    __syncthreads();
    for (int off = 1; off < 256; off <<= 1) {
        int u = (t >= off) ? excl[t - off] : 0;
        __syncthreads();
        excl[t] += u;
        __syncthreads();
    }
    int ex = excl[t] - v;
    excl[t] = ex;
    cur[t] = 0;
    int row = (b << 8) + t;
    if (row < M) row_ptr[row] = beg + ex;
    __syncthreads();
    for (int j = beg + t; j < endi; j += 256) {
        int2 p = tmp[j];
        int dl = (p.x >> 17) & 255;
        int pos = beg + excl[dl] + atomicAdd(&cur[dl], 1);
        pairs[pos] = p;
    }
}

// ---------------- FUSED layer-1 gather + relu + GEMM2 ----------------
// Block = 16 dst rows. Phase 1: 16-lane group gathers one h-row (relu, bf16)
// into XOR-swizzled LDS. Phase 2: each wave computes a 16x16 tile of h @ W2
// (K=128, 4 MFMA) and writes sup2 directly. h never touches global memory.
__global__ __launch_bounds__(256) void spmm_gemm2_fused_kernel(
    const int*  __restrict__ row_ptr,
    const int2* __restrict__ pairs,
    const unsigned short* __restrict__ dense,   // sup_bf  [M][128]
    const unsigned short* __restrict__ W2T,     // [64][128] bf16 (L1-resident)
    unsigned short*       __restrict__ sup2,    // [M][64] bf16 = relu(spmm(sup)) @ W2
    int M)
{
    __shared__ unsigned short hs[16 * 128];     // 4KB, swizzled: byte ^= (r&7)<<4
    const int wv = threadIdx.x >> 6, l = threadIdx.x & 63;
    const int g = l >> 4, t = l & 15;
    const int row = blockIdx.x * 16 + wv * 4 + g;
    int beg = 0, end = 0;
    if (row < M) { beg = row_ptr[row]; end = row_ptr[row + 1]; }
    const uint4* d4 = reinterpret_cast<const uint4*>(dense);  // row = 16 uint4
    float2 a0 = {0.f, 0.f}, a1 = {0.f, 0.f}, a2 = {0.f, 0.f}, a3 = {0.f, 0.f};
    int j = beg;
    for (; j + 4 <= end; j += 4) {
        int2 p0 = pairs[j], p1 = pairs[j + 1], p2 = pairs[j + 2], p3 = pairs[j + 3];
        uint4 x0 = d4[(size_t)(p0.x & 0x1FFFF) * 16 + t];
        uint4 x1 = d4[(size_t)(p1.x & 0x1FFFF) * 16 + t];
        uint4 x2 = d4[(size_t)(p2.x & 0x1FFFF) * 16 + t];
        uint4 x3 = d4[(size_t)(p3.x & 0x1FFFF) * 16 + t];
        float v0 = __int_as_float(p0.y), v1 = __int_as_float(p1.y);
        float v2 = __int_as_float(p2.y), v3 = __int_as_float(p3.y);
        a0.x += v0 * bf_lo(x0.x); a0.y += v0 * bf_hi(x0.x);
        a1.x += v0 * bf_lo(x0.y); a1.y += v0 * bf_hi(x0.y);
        a2.x += v0 * bf_lo(x0.z); a2.y += v0 * bf_hi(x0.z);
        a3.x += v0 * bf_lo(x0.w); a3.y += v0 * bf_hi(x0.w);
        a0.x += v1 * bf_lo(x1.x); a0.y += v1 * bf_hi(x1.x);
        a1.x += v1 * bf_lo(x1.y); a1.y += v1 * bf_hi(x1.y);
        a2.x += v1 * bf_lo(x1.z); a2.y += v1 * bf_hi(x1.z);
        a3.x += v1 * bf_lo(x1.w); a3.y += v1 * bf_hi(x1.w);
        a0.x += v2 * bf_lo(x2.x); a0.y += v2 * bf_hi(x2.x);
        a1.x += v2 * bf_lo(x2.y); a1.y += v2 * bf_hi(x2.y);
        a2.x += v2 * bf_lo(x2.z); a2.y += v2 * bf_hi(x2.z);
        a3.x += v2 * bf_lo(x2.w); a3.y += v2 * bf_hi(x2.w);
        a0.x += v3 * bf_lo(x3.x); a0.y += v3 * bf_hi(x3.x);
        a1.x += v3 * bf_lo(x3.y); a1.y += v3 * bf_hi(x3.y);
        a2.x += v3 * bf_lo(x3.z); a2.y += v3 * bf_hi(x3.z);
        a3.x += v3 * bf_lo(x3.w); a3.y += v3 * bf_hi(x3.w);
    }
    for (; j < end; ++j) {
        int2 p = pairs[j];
        uint4 x = d4[(size_t)(p.x & 0x1FFFF) * 16 + t];
        float v = __int_as_float(p.y);
        a0.x += v * bf_lo(x.x); a0.y += v * bf_hi(x.x);
        a1.x += v * bf_lo(x.y); a1.y += v * bf_hi(x.y);
        a2.x += v * bf_lo(x.z); a2.y += v * bf_hi(x.z);
        a3.x += v * bf_lo(x.w); a3.y += v * bf_hi(x.w);
    }
    {   // write relu'd h row into swizzled LDS (garbage rows masked at output)
        uint4 o;
        o.x = (unsigned)f2bf(fmaxf(a0.x, 0.f)) | ((unsigned)f2bf(fmaxf(a0.y, 0.f)) << 16);
        o.y = (unsigned)f2bf(fmaxf(a1.x, 0.f)) | ((unsigned)f2bf(fmaxf(a1.y, 0.f)) << 16);
        o.z = (unsigned)f2bf(fmaxf(a2.x, 0.f)) | ((unsigned)f2bf(fmaxf(a2.y, 0.f)) << 16);
        o.w = (unsigned)f2bf(fmaxf(a3.x, 0.f)) | ((unsigned)f2bf(fmaxf(a3.y, 0.f)) << 16);
        const int rloc = wv * 4 + g;
        const int byte = (t * 16) ^ ((rloc & 7) << 4);
        *reinterpret_cast<uint4*>(reinterpret_cast<char*>(hs) + rloc * 256 + byte) = o;
    }
    __syncthreads();
    // mini-GEMM: wave wv -> 16 rows x cols [wv*16, wv*16+16), K=128 (4 MFMA)
    floatx4 acc = (floatx4){0.f, 0.f, 0.f, 0.f};
    const int lr = l & 15, lk = l >> 4;
    #pragma unroll
    for (int ks = 0; ks < 4; ++ks) {
        const int byte = (ks * 64 + lk * 16) ^ ((lr & 7) << 4);
        short8 a = *reinterpret_cast<const short8*>(reinterpret_cast<const char*>(hs) + lr * 256 + byte);
        short8 b = *reinterpret_cast<const short8*>(W2T + (size_t)(wv * 16 + lr) * NHID + ks * 32 + lk * 8);
        acc = __builtin_amdgcn_mfma_f32_16x16x32_bf16(a, b, acc, 0, 0, 0);
    }
    const int cr = lk * 4, cc = lr;
    #pragma unroll
    for (int q = 0; q < 4; ++q) {
        int orow = blockIdx.x * 16 + cr + q;
        if (orow < M) sup2[(size_t)orow * NCLASS + wv * 16 + cc] = f2bf(acc[q]);
    }
}

// ---------------- layer-2 gather: D=64, 8-lane group per dst row, f32 out ----------------
__global__ __launch_bounds__(256) void spmm_gather64_kernel(
    const int*  __restrict__ row_ptr,
    const int2* __restrict__ pairs,
    const unsigned short* __restrict__ dense,   // bf16 [M][64]
    float*                __restrict__ out,     // f32 [M][64]
    int M)
{
    const int wv = threadIdx.x >> 6, l = threadIdx.x & 63;
    const int g = l >> 3, t = l & 7;
    const int row = blockIdx.x * 32 + wv * 8 + g;
    int beg = 0, end = 0;
    if (row < M) { beg = row_ptr[row]; end = row_ptr[row + 1]; }
    const uint4* d4 = reinterpret_cast<const uint4*>(dense);  // row = 8 uint4
    float2 a0 = {0.f, 0.f}, a1 = {0.f, 0.f}, a2 = {0.f, 0.f}, a3 = {0.f, 0.f};
    int j = beg;
    for (; j + 4 <= end; j += 4) {
        int2 p0 = pairs[j], p1 = pairs[j + 1], p2 = pairs[j + 2], p3 = pairs[j + 3];
        uint4 x0 = d4[(size_t)(p0.x & 0x1FFFF) * 8 + t];
        uint4 x1 = d4[(size_t)(p1.x & 0x1FFFF) * 8 + t];
        uint4 x2 = d4[(size_t)(p2.x & 0x1FFFF) * 8 + t];
        uint4 x3 = d4[(size_t)(p3.x & 0x1FFFF) * 8 + t];
        float v0 = __int_as_float(p0.y), v1 = __int_as_float(p1.y);
        float v2 = __int_as_float(p2.y), v3 = __int_as_float(p3.y);
        a0.x += v0 * bf_lo(x0.x); a0.y += v0 * bf_hi(x0.x);
        a1.x += v0 * bf_lo(x0.y); a1.y += v0 * bf_hi(x0.y);
        a2.x += v0 * bf_lo(x0.z); a2.y += v0 * bf_hi(x0.z);
        a3.x += v0 * bf_lo(x0.w); a3.y += v0 * bf_hi(x0.w);
        a0.x += v1 * bf_lo(x1.x); a0.y += v1 * bf_hi(x1.x);
        a1.x += v1 * bf_lo(x1.y); a1.y += v1 * bf_hi(x1.y);
        a2.x += v1 * bf_lo(x1.z); a2.y += v1 * bf_hi(x1.z);
        a3.x += v1 * bf_lo(x1.w); a3.y += v1 * bf_hi(x1.w);
        a0.x += v2 * bf_lo(x2.x); a0.y += v2 * bf_hi(x2.x);
        a1.x += v2 * bf_lo(x2.y); a1.y += v2 * bf_hi(x2.y);
        a2.x += v2 * bf_lo(x2.z); a2.y += v2 * bf_hi(x2.z);
        a3.x += v2 * bf_lo(x2.w); a3.y += v2 * bf_hi(x2.w);
        a0.x += v3 * bf_lo(x3.x); a0.y += v3 * bf_hi(x3.x);
        a1.x += v3 * bf_lo(x3.y); a1.y += v3 * bf_hi(x3.y);
        a2.x += v3 * bf_lo(x3.z); a2.y += v3 * bf_hi(x3.z);
        a3.x += v3 * bf_lo(x3.w); a3.y += v3 * bf_hi(x3.w);
    }
    for (; j < end; ++j) {
        int2 p = pairs[j];
        uint4 x = d4[(size_t)(p.x & 0x1FFFF) * 8 + t];
        float v = __int_as_float(p.y);
        a0.x += v * bf_lo(x.x); a0.y += v * bf_hi(x.x);
        a1.x += v * bf_lo(x.y); a1.y += v * bf_hi(x.y);
        a2.x += v * bf_lo(x.z); a2.y += v * bf_hi(x.z);
        a3.x += v * bf_lo(x.w); a3.y += v * bf_hi(x.w);
    }
    if (row < M) {
        float4 o0 = make_float4(a0.x, a0.y, a1.x, a1.y);
        float4 o1 = make_float4(a2.x, a2.y, a3.x, a3.y);
        float4* op = reinterpret_cast<float4*>(out + (size_t)row * 64 + t * 8);
        op[0] = o0;
        op[1] = o1;
    }
}

extern "C" void kernel_launch(void* const* d_in, const int* in_sizes, int n_in,
                              void* d_out, int out_size, void* d_ws, size_t ws_size,
                              hipStream_t stream) {
    const float* x  = (const float*)d_in[0];
    const float* W1 = (const float*)d_in[1];
    const float* W2 = (const float*)d_in[2];
    const float* ev = (const float*)d_in[3];
    const int*   es = (const int*)d_in[4];
    const int*   ed = (const int*)d_in[5];
    float* out = (float*)d_out;

    const int M = in_sizes[0] / NFEAT;   // 100000
    const int E = in_sizes[3];           // 1.6M
    const int nbuk = (M + 255) >> 8;     // 391

    size_t off = 0;
    auto alloc = [&](size_t bytes) -> void* {
        void* p = (char*)d_ws + off;
        off += (bytes + 255) & ~(size_t)255;
        return p;
    };
    unsigned short* sup_bf  = (unsigned short*)alloc((size_t)M * NHID * 2);
    unsigned short* sup2_bf = (unsigned short*)alloc((size_t)M * NCLASS * 2);
    unsigned short* W1T     = (unsigned short*)alloc((size_t)NHID * NFEAT * 2);
    unsigned short* W2T     = (unsigned short*)alloc((size_t)NCLASS * NHID * 2);
    int*  row_ptr = (int*) alloc((size_t)(M + 1) * sizeof(int));
    int*  bcnt    = (int*) alloc(512 * sizeof(int));
    int*  bb      = (int*) alloc(513 * sizeof(int));
    int*  bcur    = (int*) alloc(512 * sizeof(int));
    int2* tmp     = (int2*)alloc((size_t)E * sizeof(int2));
    int2* pairs   = (int2*)alloc((size_t)E * sizeof(int2));
    (void)ws_size;

    const int pgrid = (E + EPB - 1) / EPB;
    const int castg = (NFEAT * NHID + 255) / 256;

    // bucket count + weight cast fused (independent work)
    hipMemsetAsync(bcnt, 0, 512 * sizeof(int), stream);
    fused_cast_count_kernel<<<pgrid + castg, 256, 0, stream>>>(
        ed, bcnt, E, nbuk, pgrid, W1, W2, W1T, W2T);

    // GEMM1 (proven round-5 kernel): sup_bf = bf16(x @ W1)
    gemm_mfma_kernel<NHID, NFEAT, true><<<(M + 63) / 64, 256, 0, stream>>>(x, W1T, sup_bf, M);

    // CSR build
    bucket_scan_kernel<<<1, 512, 0, stream>>>(bcnt, bb, bcur, row_ptr, nbuk, M, E);
    bucket_scatter_kernel<<<pgrid, 256, 0, stream>>>(ev, es, ed, bcur, tmp, E);
    bucket_fine_kernel<<<nbuk, 256, 0, stream>>>(bb, tmp, row_ptr, pairs, M);

    // FUSED: sup2 = relu(spmm(A, sup)) @ W2   (h never hits HBM)
    spmm_gemm2_fused_kernel<<<(M + 15) / 16, 256, 0, stream>>>(
        row_ptr, pairs, sup_bf, W2T, sup2_bf, M);

    // layer-2 aggregate -> f32 out
    spmm_gather64_kernel<<<(M + 31) / 32, 256, 0, stream>>>(row_ptr, pairs, sup2_bf, out, M);
}

// Round 11
// 180.598 us; speedup vs baseline: 1.4329x; 1.1548x over previous
//
#include <hip/hip_runtime.h>

constexpr int NFEAT  = 256;
constexpr int NHID   = 128;
constexpr int NCLASS = 64;

typedef __attribute__((ext_vector_type(8))) short short8;   // 8 bf16 (4 VGPRs)
typedef __attribute__((ext_vector_type(4))) float floatx4;  // MFMA accumulator

__device__ __forceinline__ unsigned short f2bf(float x) {
    unsigned u = __float_as_uint(x);
    u += 0x7FFFu + ((u >> 16) & 1u);   // RNE
    return (unsigned short)(u >> 16);
}
__device__ __forceinline__ float bf_lo(unsigned int p) { return __uint_as_float(p << 16); }
__device__ __forceinline__ float bf_hi(unsigned int p) { return __uint_as_float(p & 0xFFFF0000u); }

constexpr int EPB = 8192;   // edges per partition block

// ---------------- fused: bucket histogram (blocks < pgrid) + W cast (rest) ----------------
__global__ __launch_bounds__(256) void fused_cast_count_kernel(
    const int* __restrict__ dst, int* __restrict__ bcnt, int E, int nbuk, int pgrid,
    const float* __restrict__ W1, const float* __restrict__ W2,
    unsigned short* __restrict__ W1T, unsigned short* __restrict__ W2T)
{
    __shared__ int cnt[512];
    if ((int)blockIdx.x < pgrid) {
        for (int i = threadIdx.x; i < 512; i += 256) cnt[i] = 0;
        __syncthreads();
        int begin = blockIdx.x * EPB;
        int endi = begin + EPB; if (endi > E) endi = E;
        for (int i = begin + threadIdx.x; i < endi; i += 256)
            atomicAdd(&cnt[dst[i] >> 8], 1);
        __syncthreads();
        for (int b = threadIdx.x; b < nbuk; b += 256)
            if (cnt[b]) atomicAdd(&bcnt[b], cnt[b]);
    } else {
        int i = (blockIdx.x - pgrid) * 256 + threadIdx.x;
        if (i < NFEAT * NHID) {         // 256x128
            int k = i >> 7, n = i & 127;
            W1T[n * NFEAT + k] = f2bf(W1[i]);
        }
        if (i < NHID * NCLASS) {        // 128x64
            int k = i >> 6, n = i & 63;
            W2T[n * NHID + k] = f2bf(W2[i]);
        }
    }
}

// ---------------- FUSED: bucket_scatter (blocks < sgrid) + GEMM1 (rest) ----------------
// Independent workloads share one grid so scatter's memory phase overlaps
// gemm1's latency-bound stream. GEMM1 body = round-5 proven 63us structure.
__global__ __launch_bounds__(256) void gemm1_scatter_fused_kernel(
    const float* __restrict__ A,               // x [M][256] f32
    const unsigned short* __restrict__ BT,     // W1T [128][256] bf16
    unsigned short* __restrict__ C,            // sup [M][128] bf16
    int M,
    const float* __restrict__ vals, const int* __restrict__ src,
    const int* __restrict__ dst, int* __restrict__ bcur,
    int2* __restrict__ tmp, int E, int sgrid)
{
    constexpr int KTOT = NFEAT, BN = NHID;
    constexpr int NB  = BN / 16;
    constexpr int LDA = 72;
    __shared__ unsigned short smem[64 * LDA + BN * LDA];   // 27648 B (gemm1) >= 4KB (scatter)

    if ((int)blockIdx.x < sgrid) {
        // ---- scatter body ----
        int* cnt  = reinterpret_cast<int*>(smem);
        int* base = cnt + 512;
        for (int i = threadIdx.x; i < 512; i += 256) cnt[i] = 0;
        __syncthreads();
        int begin = blockIdx.x * EPB;
        int endi = begin + EPB; if (endi > E) endi = E;
        for (int i = begin + threadIdx.x; i < endi; i += 256)
            atomicAdd(&cnt[dst[i] >> 8], 1);
        __syncthreads();
        for (int b = threadIdx.x; b < 512; b += 256) {
            int c = cnt[b];
            base[b] = c ? atomicAdd(&bcur[b], c) : 0;
            cnt[b] = 0;
        }
        __syncthreads();
        for (int i = begin + threadIdx.x; i < endi; i += 256) {
            int d = dst[i];
            int b = d >> 8;
            int pos = base[b] + atomicAdd(&cnt[b], 1);
            tmp[pos] = make_int2(src[i] | ((d & 255) << 17), __float_as_int(vals[i]));
        }
        return;
    }

    // ---- GEMM1 body ----
    unsigned short* As = smem;
    unsigned short* Bs = smem + 64 * LDA;
    const int tid = threadIdx.x;
    const int w   = tid >> 6;
    const int l   = tid & 63;
    const int row0 = ((int)blockIdx.x - sgrid) * 64;

    floatx4 acc[NB];
    #pragma unroll
    for (int i = 0; i < NB; ++i) acc[i] = (floatx4){0.f, 0.f, 0.f, 0.f};

    for (int k0 = 0; k0 < KTOT; k0 += 64) {
        #pragma unroll
        for (int i = 0; i < 4; ++i) {
            int c = tid + 256 * i;
            int r = c >> 4, k4 = (c & 15) * 4;
            int row = row0 + r;
            float4 v = (row < M) ? *reinterpret_cast<const float4*>(A + (size_t)row * KTOT + k0 + k4)
                                 : make_float4(0.f, 0.f, 0.f, 0.f);
            ushort4 b;
            b.x = f2bf(v.x); b.y = f2bf(v.y); b.z = f2bf(v.z); b.w = f2bf(v.w);
            *reinterpret_cast<ushort4*>(&As[r * LDA + k4]) = b;
        }
        #pragma unroll
        for (int i = 0; i < BN * 8 / 256; ++i) {
            int c = tid + 256 * i;
            int n = c >> 3, k8 = (c & 7) * 8;
            uint4 v = *reinterpret_cast<const uint4*>(BT + (size_t)n * KTOT + k0 + k8);
            *reinterpret_cast<uint4*>(&Bs[n * LDA + k8]) = v;
        }
        __syncthreads();
        #pragma unroll
        for (int ks = 0; ks < 2; ++ks) {
            short8 a = *reinterpret_cast<const short8*>(&As[(16 * w + (l & 15)) * LDA + ks * 32 + (l >> 4) * 8]);
            #pragma unroll
            for (int nb = 0; nb < NB; ++nb) {
                short8 b = *reinterpret_cast<const short8*>(&Bs[(16 * nb + (l & 15)) * LDA + ks * 32 + (l >> 4) * 8]);
                acc[nb] = __builtin_amdgcn_mfma_f32_16x16x32_bf16(a, b, acc[nb], 0, 0, 0);
            }
        }
        __syncthreads();
    }
    const int cr = (l >> 4) * 4;
    const int cc = l & 15;
    #pragma unroll
    for (int nb = 0; nb < NB; ++nb) {
        #pragma unroll
        for (int r = 0; r < 4; ++r) {
            int row = row0 + 16 * w + cr + r;
            if (row < M) C[(size_t)row * BN + 16 * nb + cc] = f2bf(acc[nb][r]);
        }
    }
}

// ---------------- CSR build remainder ----------------

__global__ __launch_bounds__(512) void bucket_scan_kernel(
    const int* __restrict__ bcnt, int* __restrict__ bb, int* __restrict__ bcur,
    int* __restrict__ row_ptr, int nbuk, int M, int E)
{
    __shared__ int s[512];
    int t = threadIdx.x;
    int v = (t < nbuk) ? bcnt[t] : 0;
    s[t] = v;
    __syncthreads();
    for (int off = 1; off < 512; off <<= 1) {
        int u = (t >= off) ? s[t - off] : 0;
        __syncthreads();
        s[t] += u;
        __syncthreads();
    }
    if (t < nbuk) {
        int excl = s[t] - v;
        bb[t] = excl;
        bcur[t] = excl;
    }
    if (t == 0) { bb[nbuk] = E; row_ptr[M] = E; }
}

__global__ __launch_bounds__(256) void bucket_fine_kernel(
    const int* __restrict__ bb, const int2* __restrict__ tmp,
    int* __restrict__ row_ptr, int2* __restrict__ pairs, int M)
{
    __shared__ int cnt[256];
    __shared__ int excl[256];
    __shared__ int cur[256];
    const int b = blockIdx.x;
    const int beg = bb[b], endi = bb[b + 1];
    const int t = threadIdx.x;
    cnt[t] = 0;
    __syncthreads();
    for (int j = beg + t; j < endi; j += 256)
        atomicAdd(&cnt[(tmp[j].x >> 17) & 255], 1);
    __syncthreads();
    int v = cnt[t];
    excl[t] = v;
    __syncthreads();
    for (int off = 1; off < 256; off <<= 1) {
        int u = (t >= off) ? excl[t - off] : 0;
        __syncthreads();
        excl[t] += u;
        __syncthreads();
    }
    int ex = excl[t] - v;
    excl[t] = ex;
    cur[t] = 0;
    int row = (b << 8) + t;
    if (row < M) row_ptr[row] = beg + ex;
    __syncthreads();
    for (int j = beg + t; j < endi; j += 256) {
        int2 p = tmp[j];
        int dl = (p.x >> 17) & 255;
        int pos = beg + excl[dl] + atomicAdd(&cur[dl], 1);
        pairs[pos] = p;
    }
}

// ---------------- FUSED layer-1 gather + relu + GEMM2 ----------------
__global__ __launch_bounds__(256) void spmm_gemm2_fused_kernel(
    const int*  __restrict__ row_ptr,
    const int2* __restrict__ pairs,
    const unsigned short* __restrict__ dense,   // sup_bf  [M][128]
    const unsigned short* __restrict__ W2T,     // [64][128] bf16 (L1-resident)
    unsigned short*       __restrict__ sup2,    // [M][64] bf16 = relu(spmm(sup)) @ W2
    int M)
{
    __shared__ unsigned short hs[16 * 128];     // 4KB, swizzled: byte ^= (r&7)<<4
    const int wv = threadIdx.x >> 6, l = threadIdx.x & 63;
    const int g = l >> 4, t = l & 15;
    const int row = blockIdx.x * 16 + wv * 4 + g;
    int beg = 0, end = 0;
    if (row < M) { beg = row_ptr[row]; end = row_ptr[row + 1]; }
    const uint4* d4 = reinterpret_cast<const uint4*>(dense);  // row = 16 uint4
    float2 a0 = {0.f, 0.f}, a1 = {0.f, 0.f}, a2 = {0.f, 0.f}, a3 = {0.f, 0.f};
    int j = beg;
    for (; j + 4 <= end; j += 4) {
        int2 p0 = pairs[j], p1 = pairs[j + 1], p2 = pairs[j + 2], p3 = pairs[j + 3];
        uint4 x0 = d4[(size_t)(p0.x & 0x1FFFF) * 16 + t];
        uint4 x1 = d4[(size_t)(p1.x & 0x1FFFF) * 16 + t];
        uint4 x2 = d4[(size_t)(p2.x & 0x1FFFF) * 16 + t];
        uint4 x3 = d4[(size_t)(p3.x & 0x1FFFF) * 16 + t];
        float v0 = __int_as_float(p0.y), v1 = __int_as_float(p1.y);
        float v2 = __int_as_float(p2.y), v3 = __int_as_float(p3.y);
        a0.x += v0 * bf_lo(x0.x); a0.y += v0 * bf_hi(x0.x);
        a1.x += v0 * bf_lo(x0.y); a1.y += v0 * bf_hi(x0.y);
        a2.x += v0 * bf_lo(x0.z); a2.y += v0 * bf_hi(x0.z);
        a3.x += v0 * bf_lo(x0.w); a3.y += v0 * bf_hi(x0.w);
        a0.x += v1 * bf_lo(x1.x); a0.y += v1 * bf_hi(x1.x);
        a1.x += v1 * bf_lo(x1.y); a1.y += v1 * bf_hi(x1.y);
        a2.x += v1 * bf_lo(x1.z); a2.y += v1 * bf_hi(x1.z);
        a3.x += v1 * bf_lo(x1.w); a3.y += v1 * bf_hi(x1.w);
        a0.x += v2 * bf_lo(x2.x); a0.y += v2 * bf_hi(x2.x);
        a1.x += v2 * bf_lo(x2.y); a1.y += v2 * bf_hi(x2.y);
        a2.x += v2 * bf_lo(x2.z); a2.y += v2 * bf_hi(x2.z);
        a3.x += v2 * bf_lo(x2.w); a3.y += v2 * bf_hi(x2.w);
        a0.x += v3 * bf_lo(x3.x); a0.y += v3 * bf_hi(x3.x);
        a1.x += v3 * bf_lo(x3.y); a1.y += v3 * bf_hi(x3.y);
        a2.x += v3 * bf_lo(x3.z); a2.y += v3 * bf_hi(x3.z);
        a3.x += v3 * bf_lo(x3.w); a3.y += v3 * bf_hi(x3.w);
    }
    for (; j < end; ++j) {
        int2 p = pairs[j];
        uint4 x = d4[(size_t)(p.x & 0x1FFFF) * 16 + t];
        float v = __int_as_float(p.y);
        a0.x += v * bf_lo(x.x); a0.y += v * bf_hi(x.x);
        a1.x += v * bf_lo(x.y); a1.y += v * bf_hi(x.y);
        a2.x += v * bf_lo(x.z); a2.y += v * bf_hi(x.z);
        a3.x += v * bf_lo(x.w); a3.y += v * bf_hi(x.w);
    }
    {   // write relu'd h row into swizzled LDS (garbage rows masked at output)
        uint4 o;
        o.x = (unsigned)f2bf(fmaxf(a0.x, 0.f)) | ((unsigned)f2bf(fmaxf(a0.y, 0.f)) << 16);
        o.y = (unsigned)f2bf(fmaxf(a1.x, 0.f)) | ((unsigned)f2bf(fmaxf(a1.y, 0.f)) << 16);
        o.z = (unsigned)f2bf(fmaxf(a2.x, 0.f)) | ((unsigned)f2bf(fmaxf(a2.y, 0.f)) << 16);
        o.w = (unsigned)f2bf(fmaxf(a3.x, 0.f)) | ((unsigned)f2bf(fmaxf(a3.y, 0.f)) << 16);
        const int rloc = wv * 4 + g;
        const int byte = (t * 16) ^ ((rloc & 7) << 4);
        *reinterpret_cast<uint4*>(reinterpret_cast<char*>(hs) + rloc * 256 + byte) = o;
    }
    __syncthreads();
    // mini-GEMM: wave wv -> 16 rows x cols [wv*16, wv*16+16), K=128 (4 MFMA)
    floatx4 acc = (floatx4){0.f, 0.f, 0.f, 0.f};
    const int lr = l & 15, lk = l >> 4;
    #pragma unroll
    for (int ks = 0; ks < 4; ++ks) {
        const int byte = (ks * 64 + lk * 16) ^ ((lr & 7) << 4);
        short8 a = *reinterpret_cast<const short8*>(reinterpret_cast<const char*>(hs) + lr * 256 + byte);
        short8 b = *reinterpret_cast<const short8*>(W2T + (size_t)(wv * 16 + lr) * NHID + ks * 32 + lk * 8);
        acc = __builtin_amdgcn_mfma_f32_16x16x32_bf16(a, b, acc, 0, 0, 0);
    }
    const int cr = lk * 4, cc = lr;
    #pragma unroll
    for (int q = 0; q < 4; ++q) {
        int orow = blockIdx.x * 16 + cr + q;
        if (orow < M) sup2[(size_t)orow * NCLASS + wv * 16 + cc] = f2bf(acc[q]);
    }
}

// ---------------- layer-2 gather: D=64, 8-lane group per dst row, f32 out ----------------
__global__ __launch_bounds__(256) void spmm_gather64_kernel(
    const int*  __restrict__ row_ptr,
    const int2* __restrict__ pairs,
    const unsigned short* __restrict__ dense,   // bf16 [M][64]
    float*                __restrict__ out,     // f32 [M][64]
    int M)
{
    const int wv = threadIdx.x >> 6, l = threadIdx.x & 63;
    const int g = l >> 3, t = l & 7;
    const int row = blockIdx.x * 32 + wv * 8 + g;
    int beg = 0, end = 0;
    if (row < M) { beg = row_ptr[row]; end = row_ptr[row + 1]; }
    const uint4* d4 = reinterpret_cast<const uint4*>(dense);  // row = 8 uint4
    float2 a0 = {0.f, 0.f}, a1 = {0.f, 0.f}, a2 = {0.f, 0.f}, a3 = {0.f, 0.f};
    int j = beg;
    for (; j + 4 <= end; j += 4) {
        int2 p0 = pairs[j], p1 = pairs[j + 1], p2 = pairs[j + 2], p3 = pairs[j + 3];
        uint4 x0 = d4[(size_t)(p0.x & 0x1FFFF) * 8 + t];
        uint4 x1 = d4[(size_t)(p1.x & 0x1FFFF) * 8 + t];
        uint4 x2 = d4[(size_t)(p2.x & 0x1FFFF) * 8 + t];
        uint4 x3 = d4[(size_t)(p3.x & 0x1FFFF) * 8 + t];
        float v0 = __int_as_float(p0.y), v1 = __int_as_float(p1.y);
        float v2 = __int_as_float(p2.y), v3 = __int_as_float(p3.y);
        a0.x += v0 * bf_lo(x0.x); a0.y += v0 * bf_hi(x0.x);
        a1.x += v0 * bf_lo(x0.y); a1.y += v0 * bf_hi(x0.y);
        a2.x += v0 * bf_lo(x0.z); a2.y += v0 * bf_hi(x0.z);
        a3.x += v0 * bf_lo(x0.w); a3.y += v0 * bf_hi(x0.w);
        a0.x += v1 * bf_lo(x1.x); a0.y += v1 * bf_hi(x1.x);
        a1.x += v1 * bf_lo(x1.y); a1.y += v1 * bf_hi(x1.y);
        a2.x += v1 * bf_lo(x1.z); a2.y += v1 * bf_hi(x1.z);
        a3.x += v1 * bf_lo(x1.w); a3.y += v1 * bf_hi(x1.w);
        a0.x += v2 * bf_lo(x2.x); a0.y += v2 * bf_hi(x2.x);
        a1.x += v2 * bf_lo(x2.y); a1.y += v2 * bf_hi(x2.y);
        a2.x += v2 * bf_lo(x2.z); a2.y += v2 * bf_hi(x2.z);
        a3.x += v2 * bf_lo(x2.w); a3.y += v2 * bf_hi(x2.w);
        a0.x += v3 * bf_lo(x3.x); a0.y += v3 * bf_hi(x3.x);
        a1.x += v3 * bf_lo(x3.y); a1.y += v3 * bf_hi(x3.y);
        a2.x += v3 * bf_lo(x3.z); a2.y += v3 * bf_hi(x3.z);
        a3.x += v3 * bf_lo(x3.w); a3.y += v3 * bf_hi(x3.w);
    }
    for (; j < end; ++j) {
        int2 p = pairs[j];
        uint4 x = d4[(size_t)(p.x & 0x1FFFF) * 8 + t];
        float v = __int_as_float(p.y);
        a0.x += v * bf_lo(x.x); a0.y += v * bf_hi(x.x);
        a1.x += v * bf_lo(x.y); a1.y += v * bf_hi(x.y);
        a2.x += v * bf_lo(x.z); a2.y += v * bf_hi(x.z);
        a3.x += v * bf_lo(x.w); a3.y += v * bf_hi(x.w);
    }
    if (row < M) {
        float4 o0 = make_float4(a0.x, a0.y, a1.x, a1.y);
        float4 o1 = make_float4(a2.x, a2.y, a3.x, a3.y);
        float4* op = reinterpret_cast<float4*>(out + (size_t)row * 64 + t * 8);
        op[0] = o0;
        op[1] = o1;
    }
}

extern "C" void kernel_launch(void* const* d_in, const int* in_sizes, int n_in,
                              void* d_out, int out_size, void* d_ws, size_t ws_size,
                              hipStream_t stream) {
    const float* x  = (const float*)d_in[0];
    const float* W1 = (const float*)d_in[1];
    const float* W2 = (const float*)d_in[2];
    const float* ev = (const float*)d_in[3];
    const int*   es = (const int*)d_in[4];
    const int*   ed = (const int*)d_in[5];
    float* out = (float*)d_out;

    const int M = in_sizes[0] / NFEAT;   // 100000
    const int E = in_sizes[3];           // 1.6M
    const int nbuk = (M + 255) >> 8;     // 391

    size_t off = 0;
    auto alloc = [&](size_t bytes) -> void* {
        void* p = (char*)d_ws + off;
        off += (bytes + 255) & ~(size_t)255;
        return p;
    };
    unsigned short* sup_bf  = (unsigned short*)alloc((size_t)M * NHID * 2);
    unsigned short* sup2_bf = (unsigned short*)alloc((size_t)M * NCLASS * 2);
    unsigned short* W1T     = (unsigned short*)alloc((size_t)NHID * NFEAT * 2);
    unsigned short* W2T     = (unsigned short*)alloc((size_t)NCLASS * NHID * 2);
    int*  row_ptr = (int*) alloc((size_t)(M + 1) * sizeof(int));
    int*  bcnt    = (int*) alloc(512 * sizeof(int));
    int*  bb      = (int*) alloc(513 * sizeof(int));
    int*  bcur    = (int*) alloc(512 * sizeof(int));
    int2* tmp     = (int2*)alloc((size_t)E * sizeof(int2));
    int2* pairs   = (int2*)alloc((size_t)E * sizeof(int2));
    (void)ws_size;

    const int pgrid = (E + EPB - 1) / EPB;           // scatter/count blocks (196)
    const int castg = (NFEAT * NHID + 255) / 256;
    const int g1grid = (M + 63) / 64;                // gemm1 blocks (1563)

    // bucket count + weight cast fused (independent work)
    hipMemsetAsync(bcnt, 0, 512 * sizeof(int), stream);
    fused_cast_count_kernel<<<pgrid + castg, 256, 0, stream>>>(
        ed, bcnt, E, nbuk, pgrid, W1, W2, W1T, W2T);

    // bucket scan (tiny; produces bcur for scatter)
    bucket_scan_kernel<<<1, 512, 0, stream>>>(bcnt, bb, bcur, row_ptr, nbuk, M, E);

    // FUSED: scatter (first pgrid blocks) overlapped with GEMM1 (remaining blocks)
    gemm1_scatter_fused_kernel<<<pgrid + g1grid, 256, 0, stream>>>(
        x, W1T, sup_bf, M, ev, es, ed, bcur, tmp, E, pgrid);

    // per-row CSR within buckets
    bucket_fine_kernel<<<nbuk, 256, 0, stream>>>(bb, tmp, row_ptr, pairs, M);

    // FUSED: sup2 = relu(spmm(A, sup)) @ W2   (h never hits HBM)
    spmm_gemm2_fused_kernel<<<(M + 15) / 16, 256, 0, stream>>>(
        row_ptr, pairs, sup_bf, W2T, sup2_bf, M);

    // layer-2 aggregate -> f32 out
    spmm_gather64_kernel<<<(M + 31) / 32, 256, 0, stream>>>(row_ptr, pairs, sup2_bf, out, M);
}

// Round 12
// 163.873 us; speedup vs baseline: 1.5791x; 1.1021x over previous
//
#include <hip/hip_runtime.h>

constexpr int NFEAT  = 256;
constexpr int NHID   = 128;
constexpr int NCLASS = 64;

typedef __attribute__((ext_vector_type(8))) short short8;   // 8 bf16 (4 VGPRs)
typedef __attribute__((ext_vector_type(4))) float floatx4;  // MFMA accumulator

__device__ __forceinline__ unsigned short f2bf(float x) {
    unsigned u = __float_as_uint(x);
    u += 0x7FFFu + ((u >> 16) & 1u);   // RNE
    return (unsigned short)(u >> 16);
}
__device__ __forceinline__ float bf_lo(unsigned int p) { return __uint_as_float(p << 16); }
__device__ __forceinline__ float bf_hi(unsigned int p) { return __uint_as_float(p & 0xFFFF0000u); }

constexpr int EPB = 8192;   // edges per scatter block
constexpr int CAP = 8192;   // fixed bucket capacity (mean ~4092, Poisson tail << CAP)

// ---------------- K1: W cast + bcur init (block 0) ----------------
__global__ __launch_bounds__(256) void init_cast_kernel(
    const float* __restrict__ W1, const float* __restrict__ W2,
    unsigned short* __restrict__ W1T, unsigned short* __restrict__ W2T,
    int* __restrict__ bcur, int nbuk)
{
    if (blockIdx.x == 0) {
        for (int b = threadIdx.x; b < nbuk; b += 256) bcur[b] = b * CAP;
        return;
    }
    int i = ((int)blockIdx.x - 1) * 256 + threadIdx.x;
    if (i < NFEAT * NHID) {         // 256x128
        int k = i >> 7, n = i & 127;
        W1T[n * NFEAT + k] = f2bf(W1[i]);
    }
    if (i < NHID * NCLASS) {        // 128x64
        int k = i >> 6, n = i & 63;
        W2T[n * NHID + k] = f2bf(W2[i]);
    }
}

// ---------------- K2: bucket_scatter (blocks < sgrid) + GEMM1 (rest) ----------------
// Bump-allocation scatter: bcur pre-initialized to b*CAP, gapped tmp layout.
// GEMM1 body = round-5 proven 63us structure.
__global__ __launch_bounds__(256) void gemm1_scatter_fused_kernel(
    const float* __restrict__ A,               // x [M][256] f32
    const unsigned short* __restrict__ BT,     // W1T [128][256] bf16
    unsigned short* __restrict__ C,            // sup [M][128] bf16
    int M,
    const float* __restrict__ vals, const int* __restrict__ src,
    const int* __restrict__ dst, int* __restrict__ bcur,
    int2* __restrict__ tmp, int E, int sgrid)
{
    constexpr int KTOT = NFEAT, BN = NHID;
    constexpr int NB  = BN / 16;
    constexpr int LDA = 72;
    __shared__ unsigned short smem[64 * LDA + BN * LDA];   // 27648 B >= 4KB scatter use

    if ((int)blockIdx.x < sgrid) {
        // ---- scatter body (bump allocation) ----
        int* cnt  = reinterpret_cast<int*>(smem);
        int* base = cnt + 512;
        for (int i = threadIdx.x; i < 512; i += 256) cnt[i] = 0;
        __syncthreads();
        int begin = blockIdx.x * EPB;
        int endi = begin + EPB; if (endi > E) endi = E;
        for (int i = begin + threadIdx.x; i < endi; i += 256)
            atomicAdd(&cnt[dst[i] >> 8], 1);
        __syncthreads();
        for (int b = threadIdx.x; b < 512; b += 256) {
            int c = cnt[b];
            base[b] = c ? atomicAdd(&bcur[b], c) : 0;
            cnt[b] = 0;
        }
        __syncthreads();
        for (int i = begin + threadIdx.x; i < endi; i += 256) {
            int d = dst[i];
            int b = d >> 8;
            int pos = base[b] + atomicAdd(&cnt[b], 1);
            tmp[pos] = make_int2(src[i] | ((d & 255) << 17), __float_as_int(vals[i]));
        }
        return;
    }

    // ---- GEMM1 body ----
    unsigned short* As = smem;
    unsigned short* Bs = smem + 64 * LDA;
    const int tid = threadIdx.x;
    const int w   = tid >> 6;
    const int l   = tid & 63;
    const int row0 = ((int)blockIdx.x - sgrid) * 64;

    floatx4 acc[NB];
    #pragma unroll
    for (int i = 0; i < NB; ++i) acc[i] = (floatx4){0.f, 0.f, 0.f, 0.f};

    for (int k0 = 0; k0 < KTOT; k0 += 64) {
        #pragma unroll
        for (int i = 0; i < 4; ++i) {
            int c = tid + 256 * i;
            int r = c >> 4, k4 = (c & 15) * 4;
            int row = row0 + r;
            float4 v = (row < M) ? *reinterpret_cast<const float4*>(A + (size_t)row * KTOT + k0 + k4)
                                 : make_float4(0.f, 0.f, 0.f, 0.f);
            ushort4 b;
            b.x = f2bf(v.x); b.y = f2bf(v.y); b.z = f2bf(v.z); b.w = f2bf(v.w);
            *reinterpret_cast<ushort4*>(&As[r * LDA + k4]) = b;
        }
        #pragma unroll
        for (int i = 0; i < BN * 8 / 256; ++i) {
            int c = tid + 256 * i;
            int n = c >> 3, k8 = (c & 7) * 8;
            uint4 v = *reinterpret_cast<const uint4*>(BT + (size_t)n * KTOT + k0 + k8);
            *reinterpret_cast<uint4*>(&Bs[n * LDA + k8]) = v;
        }
        __syncthreads();
        #pragma unroll
        for (int ks = 0; ks < 2; ++ks) {
            short8 a = *reinterpret_cast<const short8*>(&As[(16 * w + (l & 15)) * LDA + ks * 32 + (l >> 4) * 8]);
            #pragma unroll
            for (int nb = 0; nb < NB; ++nb) {
                short8 b = *reinterpret_cast<const short8*>(&Bs[(16 * nb + (l & 15)) * LDA + ks * 32 + (l >> 4) * 8]);
                acc[nb] = __builtin_amdgcn_mfma_f32_16x16x32_bf16(a, b, acc[nb], 0, 0, 0);
            }
        }
        __syncthreads();
    }
    const int cr = (l >> 4) * 4;
    const int cc = l & 15;
    #pragma unroll
    for (int nb = 0; nb < NB; ++nb) {
        #pragma unroll
        for (int r = 0; r < 4; ++r) {
            int row = row0 + 16 * w + cr + r;
            if (row < M) C[(size_t)row * BN + 16 * nb + cc] = f2bf(acc[nb][r]);
        }
    }
}

// ---------------- K3: per-row CSR within buckets (gapped layout) ----------------
__global__ __launch_bounds__(256) void bucket_fine_kernel(
    const int* __restrict__ bcur,              // final cursors: end of bucket b
    const int2* __restrict__ tmp,
    int* __restrict__ row_beg, int* __restrict__ row_end,
    int2* __restrict__ pairs, int M)
{
    __shared__ int cnt[256];
    __shared__ int excl[256];
    __shared__ int cur[256];
    const int b = blockIdx.x;
    const int beg = b * CAP, endi = bcur[b];
    const int t = threadIdx.x;
    cnt[t] = 0;
    __syncthreads();
    for (int j = beg + t; j < endi; j += 256)
        atomicAdd(&cnt[(tmp[j].x >> 17) & 255], 1);
    __syncthreads();
    int v = cnt[t];
    excl[t] = v;
    __syncthreads();
    for (int off = 1; off < 256; off <<= 1) {
        int u = (t >= off) ? excl[t - off] : 0;
        __syncthreads();
        excl[t] += u;
        __syncthreads();
    }
    int ex = excl[t] - v;
    excl[t] = ex;
    cur[t] = 0;
    int row = (b << 8) + t;
    if (row < M) { row_beg[row] = beg + ex; row_end[row] = beg + ex + v; }
    __syncthreads();
    for (int j = beg + t; j < endi; j += 256) {
        int2 p = tmp[j];
        int dl = (p.x >> 17) & 255;
        int pos = beg + excl[dl] + atomicAdd(&cur[dl], 1);
        pairs[pos] = p;
    }
}

// ---------------- K4: FUSED layer-1 gather + relu + GEMM2 ----------------
__global__ __launch_bounds__(256) void spmm_gemm2_fused_kernel(
    const int*  __restrict__ row_beg,
    const int*  __restrict__ row_end,
    const int2* __restrict__ pairs,
    const unsigned short* __restrict__ dense,   // sup_bf  [M][128]
    const unsigned short* __restrict__ W2T,     // [64][128] bf16 (L1-resident)
    unsigned short*       __restrict__ sup2,    // [M][64] bf16 = relu(spmm(sup)) @ W2
    int M)
{
    __shared__ unsigned short hs[16 * 128];     // 4KB, swizzled: byte ^= (r&7)<<4
    const int wv = threadIdx.x >> 6, l = threadIdx.x & 63;
    const int g = l >> 4, t = l & 15;
    const int row = blockIdx.x * 16 + wv * 4 + g;
    int beg = 0, end = 0;
    if (row < M) { beg = row_beg[row]; end = row_end[row]; }
    const uint4* d4 = reinterpret_cast<const uint4*>(dense);  // row = 16 uint4
    float2 a0 = {0.f, 0.f}, a1 = {0.f, 0.f}, a2 = {0.f, 0.f}, a3 = {0.f, 0.f};
    int j = beg;
    for (; j + 4 <= end; j += 4) {
        int2 p0 = pairs[j], p1 = pairs[j + 1], p2 = pairs[j + 2], p3 = pairs[j + 3];
        uint4 x0 = d4[(size_t)(p0.x & 0x1FFFF) * 16 + t];
        uint4 x1 = d4[(size_t)(p1.x & 0x1FFFF) * 16 + t];
        uint4 x2 = d4[(size_t)(p2.x & 0x1FFFF) * 16 + t];
        uint4 x3 = d4[(size_t)(p3.x & 0x1FFFF) * 16 + t];
        float v0 = __int_as_float(p0.y), v1 = __int_as_float(p1.y);
        float v2 = __int_as_float(p2.y), v3 = __int_as_float(p3.y);
        a0.x += v0 * bf_lo(x0.x); a0.y += v0 * bf_hi(x0.x);
        a1.x += v0 * bf_lo(x0.y); a1.y += v0 * bf_hi(x0.y);
        a2.x += v0 * bf_lo(x0.z); a2.y += v0 * bf_hi(x0.z);
        a3.x += v0 * bf_lo(x0.w); a3.y += v0 * bf_hi(x0.w);
        a0.x += v1 * bf_lo(x1.x); a0.y += v1 * bf_hi(x1.x);
        a1.x += v1 * bf_lo(x1.y); a1.y += v1 * bf_hi(x1.y);
        a2.x += v1 * bf_lo(x1.z); a2.y += v1 * bf_hi(x1.z);
        a3.x += v1 * bf_lo(x1.w); a3.y += v1 * bf_hi(x1.w);
        a0.x += v2 * bf_lo(x2.x); a0.y += v2 * bf_hi(x2.x);
        a1.x += v2 * bf_lo(x2.y); a1.y += v2 * bf_hi(x2.y);
        a2.x += v2 * bf_lo(x2.z); a2.y += v2 * bf_hi(x2.z);
        a3.x += v2 * bf_lo(x2.w); a3.y += v2 * bf_hi(x2.w);
        a0.x += v3 * bf_lo(x3.x); a0.y += v3 * bf_hi(x3.x);
        a1.x += v3 * bf_lo(x3.y); a1.y += v3 * bf_hi(x3.y);
        a2.x += v3 * bf_lo(x3.z); a2.y += v3 * bf_hi(x3.z);
        a3.x += v3 * bf_lo(x3.w); a3.y += v3 * bf_hi(x3.w);
    }
    for (; j < end; ++j) {
        int2 p = pairs[j];
        uint4 x = d4[(size_t)(p.x & 0x1FFFF) * 16 + t];
        float v = __int_as_float(p.y);
        a0.x += v * bf_lo(x.x); a0.y += v * bf_hi(x.x);
        a1.x += v * bf_lo(x.y); a1.y += v * bf_hi(x.y);
        a2.x += v * bf_lo(x.z); a2.y += v * bf_hi(x.z);
        a3.x += v * bf_lo(x.w); a3.y += v * bf_hi(x.w);
    }
    {   // write relu'd h row into swizzled LDS (garbage rows masked at output)
        uint4 o;
        o.x = (unsigned)f2bf(fmaxf(a0.x, 0.f)) | ((unsigned)f2bf(fmaxf(a0.y, 0.f)) << 16);
        o.y = (unsigned)f2bf(fmaxf(a1.x, 0.f)) | ((unsigned)f2bf(fmaxf(a1.y, 0.f)) << 16);
        o.z = (unsigned)f2bf(fmaxf(a2.x, 0.f)) | ((unsigned)f2bf(fmaxf(a2.y, 0.f)) << 16);
        o.w = (unsigned)f2bf(fmaxf(a3.x, 0.f)) | ((unsigned)f2bf(fmaxf(a3.y, 0.f)) << 16);
        const int rloc = wv * 4 + g;
        const int byte = (t * 16) ^ ((rloc & 7) << 4);
        *reinterpret_cast<uint4*>(reinterpret_cast<char*>(hs) + rloc * 256 + byte) = o;
    }
    __syncthreads();
    // mini-GEMM: wave wv -> 16 rows x cols [wv*16, wv*16+16), K=128 (4 MFMA)
    floatx4 acc = (floatx4){0.f, 0.f, 0.f, 0.f};
    const int lr = l & 15, lk = l >> 4;
    #pragma unroll
    for (int ks = 0; ks < 4; ++ks) {
        const int byte = (ks * 64 + lk * 16) ^ ((lr & 7) << 4);
        short8 a = *reinterpret_cast<const short8*>(reinterpret_cast<const char*>(hs) + lr * 256 + byte);
        short8 b = *reinterpret_cast<const short8*>(W2T + (size_t)(wv * 16 + lr) * NHID + ks * 32 + lk * 8);
        acc = __builtin_amdgcn_mfma_f32_16x16x32_bf16(a, b, acc, 0, 0, 0);
    }
    const int cr = lk * 4, cc = lr;
    #pragma unroll
    for (int q = 0; q < 4; ++q) {
        int orow = blockIdx.x * 16 + cr + q;
        if (orow < M) sup2[(size_t)orow * NCLASS + wv * 16 + cc] = f2bf(acc[q]);
    }
}

// ---------------- K5: layer-2 gather, D=64, 8-lane group per dst row, f32 out ----------------
__global__ __launch_bounds__(256) void spmm_gather64_kernel(
    const int*  __restrict__ row_beg,
    const int*  __restrict__ row_end,
    const int2* __restrict__ pairs,
    const unsigned short* __restrict__ dense,   // bf16 [M][64]
    float*                __restrict__ out,     // f32 [M][64]
    int M)
{
    const int wv = threadIdx.x >> 6, l = threadIdx.x & 63;
    const int g = l >> 3, t = l & 7;
    const int row = blockIdx.x * 32 + wv * 8 + g;
    int beg = 0, end = 0;
    if (row < M) { beg = row_beg[row]; end = row_end[row]; }
    const uint4* d4 = reinterpret_cast<const uint4*>(dense);  // row = 8 uint4
    float2 a0 = {0.f, 0.f}, a1 = {0.f, 0.f}, a2 = {0.f, 0.f}, a3 = {0.f, 0.f};
    int j = beg;
    for (; j + 4 <= end; j += 4) {
        int2 p0 = pairs[j], p1 = pairs[j + 1], p2 = pairs[j + 2], p3 = pairs[j + 3];
        uint4 x0 = d4[(size_t)(p0.x & 0x1FFFF) * 8 + t];
        uint4 x1 = d4[(size_t)(p1.x & 0x1FFFF) * 8 + t];
        uint4 x2 = d4[(size_t)(p2.x & 0x1FFFF) * 8 + t];
        uint4 x3 = d4[(size_t)(p3.x & 0x1FFFF) * 8 + t];
        float v0 = __int_as_float(p0.y), v1 = __int_as_float(p1.y);
        float v2 = __int_as_float(p2.y), v3 = __int_as_float(p3.y);
        a0.x += v0 * bf_lo(x0.x); a0.y += v0 * bf_hi(x0.x);
        a1.x += v0 * bf_lo(x0.y); a1.y += v0 * bf_hi(x0.y);
        a2.x += v0 * bf_lo(x0.z); a2.y += v0 * bf_hi(x0.z);
        a3.x += v0 * bf_lo(x0.w); a3.y += v0 * bf_hi(x0.w);
        a0.x += v1 * bf_lo(x1.x); a0.y += v1 * bf_hi(x1.x);
        a1.x += v1 * bf_lo(x1.y); a1.y += v1 * bf_hi(x1.y);
        a2.x += v1 * bf_lo(x1.z); a2.y += v1 * bf_hi(x1.z);
        a3.x += v1 * bf_lo(x1.w); a3.y += v1 * bf_hi(x1.w);
        a0.x += v2 * bf_lo(x2.x); a0.y += v2 * bf_hi(x2.x);
        a1.x += v2 * bf_lo(x2.y); a1.y += v2 * bf_hi(x2.y);
        a2.x += v2 * bf_lo(x2.z); a2.y += v2 * bf_hi(x2.z);
        a3.x += v2 * bf_lo(x2.w); a3.y += v2 * bf_hi(x2.w);
        a0.x += v3 * bf_lo(x3.x); a0.y += v3 * bf_hi(x3.x);
        a1.x += v3 * bf_lo(x3.y); a1.y += v3 * bf_hi(x3.y);
        a2.x += v3 * bf_lo(x3.z); a2.y += v3 * bf_hi(x3.z);
        a3.x += v3 * bf_lo(x3.w); a3.y += v3 * bf_hi(x3.w);
    }
    for (; j < end; ++j) {
        int2 p = pairs[j];
        uint4 x = d4[(size_t)(p.x & 0x1FFFF) * 8 + t];
        float v = __int_as_float(p.y);
        a0.x += v * bf_lo(x.x); a0.y += v * bf_hi(x.x);
        a1.x += v * bf_lo(x.y); a1.y += v * bf_hi(x.y);
        a2.x += v * bf_lo(x.z); a2.y += v * bf_hi(x.z);
        a3.x += v * bf_lo(x.w); a3.y += v * bf_hi(x.w);
    }
    if (row < M) {
        float4 o0 = make_float4(a0.x, a0.y, a1.x, a1.y);
        float4 o1 = make_float4(a2.x, a2.y, a3.x, a3.y);
        float4* op = reinterpret_cast<float4*>(out + (size_t)row * 64 + t * 8);
        op[0] = o0;
        op[1] = o1;
    }
}

extern "C" void kernel_launch(void* const* d_in, const int* in_sizes, int n_in,
                              void* d_out, int out_size, void* d_ws, size_t ws_size,
                              hipStream_t stream) {
    const float* x  = (const float*)d_in[0];
    const float* W1 = (const float*)d_in[1];
    const float* W2 = (const float*)d_in[2];
    const float* ev = (const float*)d_in[3];
    const int*   es = (const int*)d_in[4];
    const int*   ed = (const int*)d_in[5];
    float* out = (float*)d_out;

    const int M = in_sizes[0] / NFEAT;   // 100000
    const int E = in_sizes[3];           // 1.6M
    const int nbuk = (M + 255) >> 8;     // 391

    size_t off = 0;
    auto alloc = [&](size_t bytes) -> void* {
        void* p = (char*)d_ws + off;
        off += (bytes + 255) & ~(size_t)255;
        return p;
    };
    unsigned short* sup_bf  = (unsigned short*)alloc((size_t)M * NHID * 2);
    unsigned short* sup2_bf = (unsigned short*)alloc((size_t)M * NCLASS * 2);
    unsigned short* W1T     = (unsigned short*)alloc((size_t)NHID * NFEAT * 2);
    unsigned short* W2T     = (unsigned short*)alloc((size_t)NCLASS * NHID * 2);
    int*  row_beg = (int*) alloc((size_t)M * sizeof(int));
    int*  row_end = (int*) alloc((size_t)M * sizeof(int));
    int*  bcur    = (int*) alloc(512 * sizeof(int));
    int2* tmp     = (int2*)alloc((size_t)nbuk * CAP * sizeof(int2));   // gapped
    int2* pairs   = (int2*)alloc((size_t)nbuk * CAP * sizeof(int2));   // gapped
    (void)ws_size;

    const int pgrid = (E + EPB - 1) / EPB;           // scatter blocks (196)
    const int castg = (NFEAT * NHID + 255) / 256;    // cast blocks (128)
    const int g1grid = (M + 63) / 64;                // gemm1 blocks (1563)

    // K1: W cast + bcur init (no count, no scan, no memset)
    init_cast_kernel<<<castg + 1, 256, 0, stream>>>(W1, W2, W1T, W2T, bcur, nbuk);

    // K2: scatter (first pgrid blocks, bump-alloc) overlapped with GEMM1
    gemm1_scatter_fused_kernel<<<pgrid + g1grid, 256, 0, stream>>>(
        x, W1T, sup_bf, M, ev, es, ed, bcur, tmp, E, pgrid);

    // K3: per-row CSR within buckets (gapped layout)
    bucket_fine_kernel<<<nbuk, 256, 0, stream>>>(bcur, tmp, row_beg, row_end, pairs, M);

    // K4: sup2 = relu(spmm(A, sup)) @ W2   (h never hits HBM)
    spmm_gemm2_fused_kernel<<<(M + 15) / 16, 256, 0, stream>>>(
        row_beg, row_end, pairs, sup_bf, W2T, sup2_bf, M);

    // K5: layer-2 aggregate -> f32 out
    spmm_gather64_kernel<<<(M + 31) / 32, 256, 0, stream>>>(
        row_beg, row_end, pairs, sup2_bf, out, M);
}